// Round 6
// baseline (79.023 us; speedup 1.0000x reference)
//
#include <hip/hip_runtime.h>

typedef __attribute__((ext_vector_type(8))) __bf16 bf16x8;
typedef __attribute__((ext_vector_type(4))) float f32x4;

#define NB 8
#define NN 2048
#define NF 256
#define NU 256

static __device__ __forceinline__ unsigned short f2bf(float f) {
    union { float f; unsigned u; } a; a.f = f;
    unsigned r = a.u + 0x7FFFu + ((a.u >> 16) & 1u);   // RNE, no NaN inputs
    return (unsigned short)(r >> 16);
}

// barrier WITHOUT vmcnt drain: LDS ops flushed (lgkmcnt), global loads stay in flight
static __device__ __forceinline__ void barrier_nodrain() {
    asm volatile("s_waitcnt lgkmcnt(0)" ::: "memory");
    __builtin_amdgcn_s_barrier();
    asm volatile("" ::: "memory");
}

// ---------------- kernel 0: W -> MFMA B-fragment layout (bf16) ---------------
// WTf[z][kc][ub][lane][e] = W_z[kc*32 + (lane>>4)*8 + e][ub*16 + (lane&15)]
__global__ __launch_bounds__(256) void wfrag_kernel(
    const float* __restrict__ Wm, const float* __restrict__ Wu,
    unsigned short* __restrict__ WTf) {
    int idx = blockIdx.x * 256 + threadIdx.x;   // 16384 total
    int l  = idx & 63;
    int ub = (idx >> 6) & 15;
    int kc = (idx >> 10) & 7;
    int z  = idx >> 13;
    const float* W = z ? Wu : Wm;
    int u  = ub * 16 + (l & 15);
    int k0 = kc * 32 + (l >> 4) * 8;
    unsigned short p[8];
#pragma unroll
    for (int e = 0; e < 8; ++e) p[e] = f2bf(W[(k0 + e) * NU + u]);
    uint4 v;
    v.x = (unsigned)p[0] | ((unsigned)p[1] << 16);
    v.y = (unsigned)p[2] | ((unsigned)p[3] << 16);
    v.z = (unsigned)p[4] | ((unsigned)p[5] << 16);
    v.w = (unsigned)p[6] | ((unsigned)p[7] << 16);
    *(uint4*)(WTf + (size_t)idx * 8) = v;
}

// ---------------- kernel 1: h = bf16(x @ W_msg), stored in B-frag order ------
// Hf[b][ib][ub][lane][e] = h[b][ib*32 + (lane>>4)*8 + e][ub*16 + (lane&15)]
__global__ __launch_bounds__(256) void h_kernel(
    const float* __restrict__ x, const unsigned short* __restrict__ WTf,
    unsigned short* __restrict__ Hf) {
    int t = threadIdx.x;
    int w = t >> 6, l = t & 63;
    int l15 = l & 15, lh = l >> 4;
    int m0 = blockIdx.x * 64 + w * 16;
    const f32x4 fz = {0.f, 0.f, 0.f, 0.f};
    f32x4 acc[16];
#pragma unroll
    for (int i = 0; i < 16; ++i) acc[i] = fz;
    const float* xrow = x + (size_t)(m0 + l15) * NF;
#pragma unroll
    for (int kc = 0; kc < 8; ++kc) {
        int k0 = kc * 32 + lh * 8;
        float4 xa = *(const float4*)(xrow + k0);
        float4 xb = *(const float4*)(xrow + k0 + 4);
        union { unsigned short s[8]; bf16x8 v; } af;
        af.s[0] = f2bf(xa.x); af.s[1] = f2bf(xa.y);
        af.s[2] = f2bf(xa.z); af.s[3] = f2bf(xa.w);
        af.s[4] = f2bf(xb.x); af.s[5] = f2bf(xb.y);
        af.s[6] = f2bf(xb.z); af.s[7] = f2bf(xb.w);
#pragma unroll
        for (int ub = 0; ub < 16; ++ub) {
            union { uint4 q; bf16x8 v; } bf;
            bf.q = *(const uint4*)(WTf + (size_t)(kc * 1024 + ub * 64 + l) * 8);
            acc[ub] = __builtin_amdgcn_mfma_f32_16x16x32_bf16(af.v, bf.v, acc[ub], 0, 0, 0);
        }
    }
    int bb = m0 >> 11;            // batch
    int n0 = m0 & (NN - 1);
    int ib = n0 >> 5;
    int kl = ((n0 & 31) >> 3) + (lh >> 1);
    int e0 = (lh & 1) * 4;
#pragma unroll
    for (int ub = 0; ub < 16; ++ub) {
        unsigned short p[4];
#pragma unroll
        for (int r = 0; r < 4; ++r) p[r] = f2bf(acc[ub][r]);
        size_t off = ((size_t)((bb * 64 + ib) * 16 + ub)) * 512 + (size_t)(kl * 16 + l15) * 8 + e0;
        uint2 v;
        v.x = (unsigned)p[0] | ((unsigned)p[1] << 16);
        v.y = (unsigned)p[2] | ((unsigned)p[3] << 16);
        *(uint2*)(Hf + off) = v;
    }
}

// ---------------- kernel 2: msg GEMM + mean + fused upd GEMM + relu ----------
// 512 blocks (2/CU) x 512 thr (8 waves, wave = j-tile 32 x u-tile 32)
// => 16 waves/CU. Chunk = 64 i-rows (K=64): stage adj int->bf16 transposed into
// XOR-swizzled LDS (uniform-8 b128 reads = wave64 floor), double-buffered, one
// lgkmcnt-only barrier per chunk. adj ring depth 4, Hf ring depth 2.
__global__ __launch_bounds__(512, 4) void msg_kernel(
    const int* __restrict__ adj, const unsigned short* __restrict__ Hf,
    const float* __restrict__ x, const unsigned short* __restrict__ WTf,
    const float* __restrict__ bias, float* __restrict__ out) {
    __shared__ unsigned short Abuf[2][64 * 32];   // 2 x 4KB: [j 0..31][i 0..63] bf16, swizzled
    __shared__ int degs[512];
    __shared__ float rdeg[32];

    int blk = blockIdx.x;
    int b = blk & 7, jt = blk >> 3;   // blk%8 = batch -> XCD-pinned Hf/L2 reuse
    int j0 = jt * 32;
    int t = threadIdx.x;
    int w = t >> 6, l = t & 63;       // w = wave id = u-tile (32 wide)
    int l15 = l & 15, lh = l >> 4;
    int jj = t & 31, ig = t >> 5;     // stage map: col j0+jj, rows ig*4..ig*4+3 (ig 0..15)

    const f32x4 fz = {0.f, 0.f, 0.f, 0.f};
    f32x4 acc[2][2];                  // [jf][ub]
#pragma unroll
    for (int a = 0; a < 2; ++a)
#pragma unroll
        for (int c = 0; c < 2; ++c) acc[a][c] = fz;

    const int* adjst = adj + (size_t)b * NN * NN + (size_t)(ig * 4) * NN + (j0 + jj);
    const unsigned short* hbase = Hf + (size_t)(b * 64 * 16 + w * 2) * 512 + (size_t)l * 8;

    int dsum = 0;
    int r0[4], r1[4], r2[4], r3[4], rz[4];   // adj ring (named: rule #20)
    uint4 hA[4], hB[4];                      // Hf ring: [ic*2+ub], 2 chunks deep

    auto LOADINT = [&](int* r, int c) {
        const int* p = adjst + (size_t)c * 64 * NN;
#pragma unroll
        for (int e = 0; e < 4; ++e) r[e] = p[(size_t)e * NN];
    };
    auto LOADH = [&](uint4* h, int c) {
#pragma unroll
        for (int ic = 0; ic < 2; ++ic)
#pragma unroll
            for (int ub = 0; ub < 2; ++ub)
                h[ic * 2 + ub] = *(const uint4*)(hbase +
                    (size_t)(c * 2 + ic) * 8192 + (size_t)ub * 512);
    };
    // stage: byte(j,i) = j*128 + ((i*2) ^ ((j&7)<<4)); one ds_write_b64/thread
    auto PACKWRITE = [&](int buf, const int* r, bool valid) {
        if (valid) dsum += r[0] + r[1] + r[2] + r[3];
        uint2 v;
        v.x = ((unsigned)(r[0] | (r[1] << 16))) * 0x3F80u;
        v.y = ((unsigned)(r[2] | (r[3] << 16))) * 0x3F80u;
        *(uint2*)((char*)(&Abuf[buf][0]) + jj * 128 + ((ig * 8) ^ ((jj & 7) << 4))) = v;
    };
    auto COMPUTE = [&](int buf, const uint4* h) {
#pragma unroll
        for (int jf = 0; jf < 2; ++jf) {
            int j = jf * 16 + l15;
            const char* row = (const char*)(&Abuf[buf][0]) + j * 128;
            int swz = (j & 7) << 4;
#pragma unroll
            for (int ic = 0; ic < 2; ++ic) {
                // K sub-block ic: bytes ic*64 + lh*16 within the 128B row (i = k)
                bf16x8 af = *(const bf16x8*)(row + ((ic * 64 + lh * 16) ^ swz));
#pragma unroll
                for (int ub = 0; ub < 2; ++ub) {
                    union { uint4 q; bf16x8 v; } bf;
                    bf.q = h[ic * 2 + ub];
                    acc[jf][ub] = __builtin_amdgcn_mfma_f32_16x16x32_bf16(
                        af, bf.v, acc[jf][ub], 0, 0, 0);
                }
            }
        }
    };

    // prologue: rz=chunk0 staged now; ring holds chunks 1..4; Hf chunks 0,1
    LOADINT(rz, 0);
    LOADINT(r0, 1); LOADINT(r1, 2); LOADINT(r2, 3); LOADINT(r3, 4);
    LOADH(hA, 0); LOADH(hB, 1);
    PACKWRITE(0, rz, true);
    barrier_nodrain();

    // 32 chunks, 4 phases per iter
#pragma unroll 1
    for (int c4 = 0; c4 < 32; c4 += 4) {
        PACKWRITE(1, r0, true);                       // stage chunk c4+1
        LOADINT(r0, (c4 + 5 < 32) ? c4 + 5 : 31);
        COMPUTE(0, hA);                               // chunk c4
        LOADH(hA, (c4 + 2 < 32) ? c4 + 2 : 31);
        barrier_nodrain();

        PACKWRITE(0, r1, true);                       // stage chunk c4+2
        LOADINT(r1, (c4 + 6 < 32) ? c4 + 6 : 31);
        COMPUTE(1, hB);                               // chunk c4+1
        LOADH(hB, (c4 + 3 < 32) ? c4 + 3 : 31);
        barrier_nodrain();

        PACKWRITE(1, r2, true);                       // stage chunk c4+3
        LOADINT(r2, (c4 + 7 < 32) ? c4 + 7 : 31);
        COMPUTE(0, hA);                               // chunk c4+2
        LOADH(hA, (c4 + 4 < 32) ? c4 + 4 : 31);
        barrier_nodrain();

        PACKWRITE(0, r3, c4 + 4 < 32);                // stage chunk c4+4 (skip dsum on last)
        LOADINT(r3, (c4 + 8 < 32) ? c4 + 8 : 31);
        COMPUTE(1, hB);                               // chunk c4+3
        LOADH(hB, (c4 + 5 < 32) ? c4 + 5 : 31);
        barrier_nodrain();
    }

    // degree reduce: deg[j] = sum over 16 ig groups
    degs[t] = dsum;
    barrier_nodrain();
    if (t < 32) {
        int d = 0;
#pragma unroll
        for (int g = 0; g < 16; ++g) d += degs[t + 32 * g];
        rdeg[t] = d > 0 ? 1.0f / (float)d : 0.0f;
    }
    barrier_nodrain();

    // scale msg accumulator by 1/deg (TF segment-mean: deg==0 -> 0)
#pragma unroll
    for (int jf = 0; jf < 2; ++jf)
#pragma unroll
        for (int rr = 0; rr < 4; ++rr) {
            float sc = rdeg[jf * 16 + lh * 4 + rr];
#pragma unroll
            for (int ub = 0; ub < 2; ++ub) acc[jf][ub][rr] *= sc;
        }

    // fused upd GEMM: acc += bf16(x_rows) @ W_upd
    const float* xb = x + ((size_t)b * NN + j0) * NF;
#pragma unroll
    for (int kc = 0; kc < 8; ++kc) {
        int k0 = kc * 32 + lh * 8;
        bf16x8 xf[2];
#pragma unroll
        for (int jf = 0; jf < 2; ++jf) {
            const float* xr = xb + (size_t)(jf * 16 + l15) * NF + k0;
            float4 xa = *(const float4*)xr;
            float4 xc = *(const float4*)(xr + 4);
            union { unsigned short sh[8]; bf16x8 v; } af;
            af.sh[0] = f2bf(xa.x); af.sh[1] = f2bf(xa.y);
            af.sh[2] = f2bf(xa.z); af.sh[3] = f2bf(xa.w);
            af.sh[4] = f2bf(xc.x); af.sh[5] = f2bf(xc.y);
            af.sh[6] = f2bf(xc.z); af.sh[7] = f2bf(xc.w);
            xf[jf] = af.v;
        }
#pragma unroll
        for (int ub = 0; ub < 2; ++ub) {
            int ubg = w * 2 + ub;
            union { uint4 q; bf16x8 v; } bf;
            bf.q = *(const uint4*)(WTf + (size_t)(8192 + kc * 1024 + ubg * 64 + l) * 8);
            acc[0][ub] = __builtin_amdgcn_mfma_f32_16x16x32_bf16(xf[0], bf.v, acc[0][ub], 0, 0, 0);
            acc[1][ub] = __builtin_amdgcn_mfma_f32_16x16x32_bf16(xf[1], bf.v, acc[1][ub], 0, 0, 0);
        }
    }

    // epilogue: + bias, relu, store
    float* ob = out + ((size_t)b * NN + j0) * NU;
#pragma unroll
    for (int jf = 0; jf < 2; ++jf)
#pragma unroll
        for (int ub = 0; ub < 2; ++ub) {
            int u = (w * 2 + ub) * 16 + l15;
            float bv = bias[u];
#pragma unroll
            for (int rr = 0; rr < 4; ++rr) {
                float v = acc[jf][ub][rr] + bv;
                ob[(size_t)(jf * 16 + lh * 4 + rr) * NU + u] = fmaxf(v, 0.f);
            }
        }
}

extern "C" void kernel_launch(void* const* d_in, const int* in_sizes, int n_in,
                              void* d_out, int out_size, void* d_ws, size_t ws_size,
                              hipStream_t stream) {
    const float* x    = (const float*)d_in[0];
    const int*   adj  = (const int*)d_in[1];
    const float* Wm   = (const float*)d_in[2];
    const float* Wu   = (const float*)d_in[3];
    const float* bias = (const float*)d_in[4];
    float* out = (float*)d_out;

    unsigned short* WTf = (unsigned short*)d_ws;                      // 256 KiB
    unsigned short* Hf  = (unsigned short*)((char*)d_ws + (1 << 18)); // 8 MiB

    wfrag_kernel<<<64, 256, 0, stream>>>(Wm, Wu, WTf);
    h_kernel<<<256, 256, 0, stream>>>(x, WTf, Hf);
    msg_kernel<<<512, 512, 0, stream>>>(adj, Hf, x, WTf, bias, out);
}